// Round 1
// baseline (123.145 us; speedup 1.0000x reference)
//
#include <hip/hip_runtime.h>
#include <math.h>

#define B_ 64
#define N_ 128
#define F_ 128
#define R_ 64
#define H_ 256
#define L_ 3
#define M_ (B_*N_)   // 8192 rows total

typedef short bf16x8 __attribute__((ext_vector_type(8)));
typedef float f32x4 __attribute__((ext_vector_type(4)));

__device__ __forceinline__ unsigned short f2bf(float f) {
    unsigned int u = __float_as_uint(f);
    u += 0x7FFF + ((u >> 16) & 1);   // round-to-nearest-even
    return (unsigned short)(u >> 16);
}
__device__ __forceinline__ float bf2f(unsigned short h) {
    return __uint_as_float(((unsigned int)h) << 16);
}

// ---- prep: fp32 -> bf16 (x + all layer weights), vectorized float4->ushort4 ----
__global__ void prep_kernel(const float* __restrict__ x,
                            const float* __restrict__ wcf,
                            const float* __restrict__ wdf,
                            const float* __restrict__ wfc,
                            unsigned short* __restrict__ xb,
                            unsigned short* __restrict__ wcfb,
                            unsigned short* __restrict__ wdfb,
                            unsigned short* __restrict__ wfcb) {
    const int NX  = M_*F_/4;     // 262144
    const int NCF = L_*H_*F_/4;  // 24576
    const int NDF = L_*H_*R_/4;  // 12288
    const int NFC = L_*F_*H_/4;  // 24576
    const int total = NX + NCF + NDF + NFC;
    for (int i = blockIdx.x*blockDim.x + threadIdx.x; i < total; i += gridDim.x*blockDim.x) {
        const float4* src; unsigned short* dst; int k;
        if (i < NX)                { src = (const float4*)x;   dst = xb;   k = i; }
        else if (i < NX+NCF)       { src = (const float4*)wcf; dst = wcfb; k = i-NX; }
        else if (i < NX+NCF+NDF)   { src = (const float4*)wdf; dst = wdfb; k = i-NX-NCF; }
        else                       { src = (const float4*)wfc; dst = wfcb; k = i-NX-NCF-NDF; }
        float4 v = src[k];
        ushort4 o; o.x=f2bf(v.x); o.y=f2bf(v.y); o.z=f2bf(v.z); o.w=f2bf(v.w);
        ((ushort4*)dst)[k] = o;
    }
}

// ---- collapse pooling tail: w_comb[f] = sum_c out_w[c]*fc0_w[c,f]; b_comb = out_w.fc0_b + out_b ----
__global__ void prep_comb_kernel(const float* __restrict__ fc0_w, const float* __restrict__ fc0_b,
                                 const float* __restrict__ out_w, const float* __restrict__ out_b,
                                 float* __restrict__ wcomb, float* __restrict__ bcomb) {
    int f = threadIdx.x;  // 0..127
    float s = 0.f;
    for (int c = 0; c < 256; ++c) s += out_w[c] * fc0_w[c*128 + f];
    wcomb[f] = s;
    if (f == 0) {
        float bb = out_b[0];
        for (int c = 0; c < 256; ++c) bb += out_w[c] * fc0_b[c];
        *bcomb = bb;
    }
}

// ---- d_sum[b,i,r] = sum_j distance[b,i,j,r]; one block per (b,i); output bf16 ----
__global__ __launch_bounds__(256)
void dsum_kernel(const float* __restrict__ dist, unsigned short* __restrict__ dsum) {
    int bi = blockIdx.x;                       // b*N + i
    const float4* src = (const float4*)(dist + (size_t)bi * (N_*R_));
    int t = threadIdx.x;
    int q = t & 15, jg = t >> 4;               // q: float4 column (16 per row), jg: j-group
    float4 a = make_float4(0.f,0.f,0.f,0.f);
    #pragma unroll
    for (int j0 = 0; j0 < N_; j0 += 16) {
        float4 v = src[(j0 + jg)*16 + q];
        a.x += v.x; a.y += v.y; a.z += v.z; a.w += v.w;
    }
    __shared__ float4 sh[256];
    sh[t] = a;
    __syncthreads();
    if (t < 16) {
        float4 s = sh[t];
        for (int g = 1; g < 16; ++g) {
            float4 v = sh[t + 16*g];
            s.x += v.x; s.y += v.y; s.z += v.z; s.w += v.w;
        }
        ushort4 o; o.x=f2bf(s.x); o.y=f2bf(s.y); o.z=f2bf(s.z); o.w=f2bf(s.w);
        ((ushort4*)(dsum + (size_t)bi * R_))[t] = o;
    }
}

// ---- fused layer: cf = x@Wcf^T+bc ; df = dsum@Wdf^T+128*bd ; h = (cf*df)@Wfc^T ; x' = h+tanh(h) ----
// 32 rows/block, 4 waves. Stage1: wave (mh=w&1, nq=w>>1) covers 16 rows x 128 cols of (32x256) p.
// Stage2: wave covers 16 rows x 64 cols of (32x128) h, K=256 from LDS p-tile.
__global__ __launch_bounds__(256)
void layer_kernel(const unsigned short* __restrict__ xin,
                  const unsigned short* __restrict__ dsum,
                  const unsigned short* __restrict__ wcf,
                  const unsigned short* __restrict__ wdf,
                  const unsigned short* __restrict__ wfc,
                  const float* __restrict__ bcf,
                  const float* __restrict__ bdf,
                  unsigned short* __restrict__ xout) {
    __shared__ unsigned short p_lds[32][264];   // +8 pad keeps ds_read_b128 conflict-light
    int t = threadIdx.x;
    int w = t >> 6, lane = t & 63;
    int lr = lane & 15, lg = lane >> 4;
    int mh = w & 1, nq = w >> 1;               // nq in {0,1}
    int rowA = blockIdx.x*32 + mh*16 + lr;

    // A-fragments: lane holds A[lr][kc*32 + lg*8 + j], 16B contiguous loads
    bf16x8 xa[4], da[2];
    #pragma unroll
    for (int kc = 0; kc < 4; ++kc)
        xa[kc] = *(const bf16x8*)(xin + (size_t)rowA*F_ + kc*32 + lg*8);
    #pragma unroll
    for (int kc = 0; kc < 2; ++kc)
        da[kc] = *(const bf16x8*)(dsum + (size_t)rowA*R_ + kc*32 + lg*8);

    // stage 1: 8 N-tiles of 16 cols each (covers 128 cols per wave)
    #pragma unroll
    for (int nt = 0; nt < 8; ++nt) {
        int ncol = nq*128 + nt*16 + lr;        // column in H=256
        f32x4 acf = {0.f,0.f,0.f,0.f}, adf = {0.f,0.f,0.f,0.f};
        #pragma unroll
        for (int kc = 0; kc < 4; ++kc) {
            bf16x8 b = *(const bf16x8*)(wcf + (size_t)ncol*F_ + kc*32 + lg*8);
            acf = __builtin_amdgcn_mfma_f32_16x16x32_bf16(xa[kc], b, acf, 0, 0, 0);
        }
        #pragma unroll
        for (int kc = 0; kc < 2; ++kc) {
            bf16x8 b = *(const bf16x8*)(wdf + (size_t)ncol*R_ + kc*32 + lg*8);
            adf = __builtin_amdgcn_mfma_f32_16x16x32_bf16(da[kc], b, adf, 0, 0, 0);
        }
        float bc = bcf[ncol];
        float bd = bdf[ncol] * 128.0f;         // n * Wdf_b, n = N = 128
        #pragma unroll
        for (int j = 0; j < 4; ++j) {
            float p = (acf[j] + bc) * (adf[j] + bd);
            p_lds[mh*16 + lg*4 + j][ncol] = f2bf(p);
        }
    }
    __syncthreads();

    // stage 2: h(32x128) = p(32x256) @ Wfc^T; wave covers cols nq*64..nq*64+63
    f32x4 ah[4] = {{0,0,0,0},{0,0,0,0},{0,0,0,0},{0,0,0,0}};
    #pragma unroll
    for (int kc = 0; kc < 8; ++kc) {
        bf16x8 ap = *(const bf16x8*)&p_lds[mh*16 + lr][kc*32 + lg*8];
        #pragma unroll
        for (int ct = 0; ct < 4; ++ct) {
            int ncol = nq*64 + ct*16 + lr;     // column in F=128
            bf16x8 b = *(const bf16x8*)(wfc + (size_t)ncol*H_ + kc*32 + lg*8);
            ah[ct] = __builtin_amdgcn_mfma_f32_16x16x32_bf16(ap, b, ah[ct], 0, 0, 0);
        }
    }
    #pragma unroll
    for (int ct = 0; ct < 4; ++ct) {
        int col = nq*64 + ct*16 + lr;
        #pragma unroll
        for (int j = 0; j < 4; ++j) {
            int row = blockIdx.x*32 + mh*16 + lg*4 + j;
            float h = ah[ct][j];
            float xo = h + tanhf(h);
            xout[(size_t)row*F_ + col] = f2bf(xo);
        }
    }
}

// ---- final: out[b] = b_comb + sum_{n,f} x3[b,n,f] * w_comb[f] ----
__global__ __launch_bounds__(256)
void final_kernel(const unsigned short* __restrict__ x3,
                  const float* __restrict__ wcomb,
                  const float* __restrict__ bcomb,
                  float* __restrict__ out) {
    int b = blockIdx.x, t = threadIdx.x;
    int f = t & 127;
    float wc = wcomb[f];
    float acc = 0.f;
    for (int n = t >> 7; n < N_; n += 2)
        acc += bf2f(x3[((size_t)b*N_ + n)*F_ + f]) * wc;
    __shared__ float sh[256];
    sh[t] = acc;
    __syncthreads();
    for (int s = 128; s > 0; s >>= 1) {
        if (t < s) sh[t] += sh[t + s];
        __syncthreads();
    }
    if (t == 0) out[b] = sh[0] + bcomb[0];
}

extern "C" void kernel_launch(void* const* d_in, const int* in_sizes, int n_in,
                              void* d_out, int out_size, void* d_ws, size_t ws_size,
                              hipStream_t stream) {
    const float* x     = (const float*)d_in[0];
    const float* dist  = (const float*)d_in[1];
    const float* wcf_w = (const float*)d_in[2];
    const float* wcf_b = (const float*)d_in[3];
    const float* wdf_w = (const float*)d_in[4];
    const float* wdf_b = (const float*)d_in[5];
    const float* wfc_w = (const float*)d_in[6];
    const float* fc0_w = (const float*)d_in[7];
    const float* fc0_b = (const float*)d_in[8];
    const float* out_w = (const float*)d_in[9];
    const float* out_b = (const float*)d_in[10];
    float* out = (float*)d_out;

    char* ws = (char*)d_ws;
    unsigned short* dsum = (unsigned short*)(ws);                              // 1 MB
    unsigned short* x0   = (unsigned short*)(ws + (1u<<20));                   // 2 MB
    unsigned short* x1   = (unsigned short*)(ws + 3u*(1u<<20));                // 2 MB
    unsigned short* wcfb = (unsigned short*)(ws + 5u*(1u<<20));                // 196608 B
    unsigned short* wdfb = (unsigned short*)(ws + 5u*(1u<<20) + 196608u);      //  98304 B
    unsigned short* wfcb = (unsigned short*)(ws + 5u*(1u<<20) + 294912u);      // 196608 B
    float* wcomb = (float*)(ws + 5u*(1u<<20) + 491520u);                       // 512 B
    float* bcomb = wcomb + 128;

    prep_kernel<<<512, 256, 0, stream>>>(x, wcf_w, wdf_w, wfc_w, x0, wcfb, wdfb, wfcb);
    prep_comb_kernel<<<1, 128, 0, stream>>>(fc0_w, fc0_b, out_w, out_b, wcomb, bcomb);
    dsum_kernel<<<M_, 256, 0, stream>>>(dist, dsum);

    layer_kernel<<<M_/32, 256, 0, stream>>>(x0, dsum,
        wcfb,              wdfb,             wfcb,
        wcf_b,             wdf_b,            x1);
    layer_kernel<<<M_/32, 256, 0, stream>>>(x1, dsum,
        wcfb + H_*F_,      wdfb + H_*R_,     wfcb + F_*H_,
        wcf_b + H_,        wdf_b + H_,       x0);
    layer_kernel<<<M_/32, 256, 0, stream>>>(x0, dsum,
        wcfb + 2*H_*F_,    wdfb + 2*H_*R_,   wfcb + 2*F_*H_,
        wcf_b + 2*H_,      wdf_b + 2*H_,     x1);

    final_kernel<<<B_, 256, 0, stream>>>(x1, wcomb, bcomb, out);
}

// Round 2
// 104.694 us; speedup vs baseline: 1.1762x; 1.1762x over previous
//
#include <hip/hip_runtime.h>
#include <math.h>

#define B_ 64
#define N_ 128
#define F_ 128
#define R_ 64
#define H_ 256
#define L_ 3
#define M_ (B_*N_)   // 8192 rows

#define DS_PAD 72    // row stride for ds_lds (144 B: 16B-aligned rows, 2-way max on b128)
#define X_PAD 136    // row stride for x_lds  (272 B = 17*16)
#define P_PAD 264    // row stride for p_lds  (528 B = 33*16)

typedef short bf16x8 __attribute__((ext_vector_type(8)));
typedef float f32x4 __attribute__((ext_vector_type(4)));

__device__ __forceinline__ unsigned short f2bf(float f) {
    unsigned int u = __float_as_uint(f);
    u += 0x7FFF + ((u >> 16) & 1);   // round-to-nearest-even
    return (unsigned short)(u >> 16);
}

__device__ __forceinline__ float tanh_fast(float h) {
    float a = fabsf(h);
    float e = __expf(-2.0f * a);                 // never overflows; ->0 for large a
    float t = (1.0f - e) * __builtin_amdgcn_rcpf(1.0f + e);
    return copysignf(t, h);
}

// ---- prep: fp32 -> bf16 for the 3 stacked weight tensors ----
__global__ void prep_w_kernel(const float* __restrict__ wcf,
                              const float* __restrict__ wdf,
                              const float* __restrict__ wfc,
                              unsigned short* __restrict__ wcfb,
                              unsigned short* __restrict__ wdfb,
                              unsigned short* __restrict__ wfcb) {
    const int NCF = L_*H_*F_/4;  // 24576 float4
    const int NDF = L_*H_*R_/4;  // 12288
    const int NFC = L_*F_*H_/4;  // 24576
    const int total = NCF + NDF + NFC;  // 61440
    for (int i = blockIdx.x*blockDim.x + threadIdx.x; i < total; i += gridDim.x*blockDim.x) {
        const float4* src; unsigned short* dst; int k;
        if (i < NCF)           { src = (const float4*)wcf; dst = wcfb; k = i; }
        else if (i < NCF+NDF)  { src = (const float4*)wdf; dst = wdfb; k = i-NCF; }
        else                   { src = (const float4*)wfc; dst = wfcb; k = i-NCF-NDF; }
        float4 v = src[k];
        ushort4 o; o.x=f2bf(v.x); o.y=f2bf(v.y); o.z=f2bf(v.z); o.w=f2bf(v.w);
        ((ushort4*)dst)[k] = o;
    }
}

// ---- collapse pooling tail: w_comb[f] = sum_c out_w[c]*fc0_w[c,f]; b_comb = out_w.fc0_b + out_b ----
__global__ void prep_comb_kernel(const float* __restrict__ fc0_w, const float* __restrict__ fc0_b,
                                 const float* __restrict__ out_w, const float* __restrict__ out_b,
                                 float* __restrict__ wcomb, float* __restrict__ bcomb) {
    int f = threadIdx.x;  // 0..127
    float s = 0.f;
    for (int c = 0; c < 256; ++c) s += out_w[c] * fc0_w[c*128 + f];
    wcomb[f] = s;
    if (f == 0) {
        float bb = out_b[0];
        for (int c = 0; c < 256; ++c) bb += out_w[c] * fc0_b[c];
        *bcomb = bb;
    }
}

// ---- mega: per block (32 rows): dsum + 3 fused DTNN layers + pooled partial ----
// 512 threads = 8 waves: mh = w&1 (16-row half), nq = w>>1 (col quarter).
__global__ __launch_bounds__(512)
void mega_kernel(const float* __restrict__ x,
                 const float* __restrict__ dist,
                 const unsigned short* __restrict__ wcfb,
                 const unsigned short* __restrict__ wdfb,
                 const unsigned short* __restrict__ wfcb,
                 const float* __restrict__ bcf,
                 const float* __restrict__ bdf,
                 const float* __restrict__ wcomb,
                 float* __restrict__ partial) {
    __shared__ __align__(16) unsigned short ds_lds[32][DS_PAD];
    __shared__ __align__(16) unsigned short x_lds[32][X_PAD];
    __shared__ __align__(16) unsigned short p_lds[32][P_PAD];

    const int blk  = blockIdx.x;
    const int t    = threadIdx.x;
    const int w    = t >> 6, lane = t & 63;
    const int lr   = lane & 15, lg = lane >> 4;
    const int mh   = w & 1,  nq = w >> 1;        // nq in 0..3

    // ---- Phase A: dsum over j for this block's 32 rows; x -> bf16 in LDS ----
    {
        const int row16 = t >> 4, q = t & 15;    // q: float4 column of R=64 (16 per row)
        // issue x loads early (independent of the dsum stream)
        const float4* xs = (const float4*)(x + (size_t)(blk*32 + row16)*F_ + q*8);
        float4 xv0 = xs[0], xv1 = xs[1];

        const float4* src = (const float4*)dist + ((size_t)(blk*32 + row16) * (N_)) * 16 + q;
        float4 a = {0.f, 0.f, 0.f, 0.f};
        #pragma unroll 8
        for (int j = 0; j < N_; ++j) {
            float4 v = src[(size_t)j * 16];
            a.x += v.x; a.y += v.y; a.z += v.z; a.w += v.w;
        }
        ushort4 o; o.x=f2bf(a.x); o.y=f2bf(a.y); o.z=f2bf(a.z); o.w=f2bf(a.w);
        *(ushort4*)&ds_lds[row16][q*4] = o;

        bf16x8 xb;
        xb[0]=f2bf(xv0.x); xb[1]=f2bf(xv0.y); xb[2]=f2bf(xv0.z); xb[3]=f2bf(xv0.w);
        xb[4]=f2bf(xv1.x); xb[5]=f2bf(xv1.y); xb[6]=f2bf(xv1.z); xb[7]=f2bf(xv1.w);
        *(bf16x8*)&x_lds[row16][q*8] = xb;
    }
    __syncthreads();

    float pool_acc = 0.f;

    #pragma unroll 1
    for (int l = 0; l < L_; ++l) {
        const unsigned short* wcf = wcfb + l*H_*F_;
        const unsigned short* wdf = wdfb + l*H_*R_;
        const unsigned short* wfc = wfcb + l*F_*H_;

        // A-fragments from LDS: lane holds A[lr][kc*32 + lg*8 + j]
        bf16x8 xa[4], da[2];
        #pragma unroll
        for (int kc = 0; kc < 4; ++kc)
            xa[kc] = *(const bf16x8*)&x_lds[mh*16 + lr][kc*32 + lg*8];
        #pragma unroll
        for (int kc = 0; kc < 2; ++kc)
            da[kc] = *(const bf16x8*)&ds_lds[mh*16 + lr][kc*32 + lg*8];

        // stage 1: wave covers 16 rows x 64 cols of p (H=256 split 4 ways by nq)
        #pragma unroll
        for (int nt = 0; nt < 4; ++nt) {
            const int ncol = nq*64 + nt*16 + lr;
            f32x4 acf = {0.f,0.f,0.f,0.f}, adf = {0.f,0.f,0.f,0.f};
            #pragma unroll
            for (int kc = 0; kc < 4; ++kc) {
                bf16x8 b = *(const bf16x8*)(wcf + (size_t)ncol*F_ + kc*32 + lg*8);
                acf = __builtin_amdgcn_mfma_f32_16x16x32_bf16(xa[kc], b, acf, 0, 0, 0);
            }
            #pragma unroll
            for (int kc = 0; kc < 2; ++kc) {
                bf16x8 b = *(const bf16x8*)(wdf + (size_t)ncol*R_ + kc*32 + lg*8);
                adf = __builtin_amdgcn_mfma_f32_16x16x32_bf16(da[kc], b, adf, 0, 0, 0);
            }
            const float bc = bcf[l*H_ + ncol];
            const float bd = bdf[l*H_ + ncol] * 128.0f;   // n * Wdf_b, n = N = 128
            #pragma unroll
            for (int j = 0; j < 4; ++j) {
                float p = (acf[j] + bc) * (adf[j] + bd);
                p_lds[mh*16 + lg*4 + j][ncol] = f2bf(p);
            }
        }
        __syncthreads();

        // stage 2: h(32x128) = p(32x256) @ Wfc^T; wave covers 32 cols (nq quarter)
        f32x4 ah[2] = {{0,0,0,0},{0,0,0,0}};
        #pragma unroll
        for (int kc = 0; kc < 8; ++kc) {
            bf16x8 ap = *(const bf16x8*)&p_lds[mh*16 + lr][kc*32 + lg*8];
            #pragma unroll
            for (int ct = 0; ct < 2; ++ct) {
                const int ncol = nq*32 + ct*16 + lr;
                bf16x8 b = *(const bf16x8*)(wfc + (size_t)ncol*H_ + kc*32 + lg*8);
                ah[ct] = __builtin_amdgcn_mfma_f32_16x16x32_bf16(ap, b, ah[ct], 0, 0, 0);
            }
        }
        __syncthreads();   // p_lds consumed; x_lds reads (regs) long done

        if (l < L_-1) {
            #pragma unroll
            for (int ct = 0; ct < 2; ++ct) {
                #pragma unroll
                for (int j = 0; j < 4; ++j) {
                    float h = ah[ct][j];
                    float xo = h + tanh_fast(h);
                    // D layout: row = mh*16 + lg*4 + j, col = nq*32 + ct*16 + lr
                    x_lds[mh*16 + lg*4 + j][nq*32 + ct*16 + lr] = f2bf(xo);
                }
            }
            __syncthreads();
        } else {
            #pragma unroll
            for (int ct = 0; ct < 2; ++ct) {
                const float wc = wcomb[nq*32 + ct*16 + lr];
                #pragma unroll
                for (int j = 0; j < 4; ++j) {
                    float h = ah[ct][j];
                    float xo = h + tanh_fast(h);
                    pool_acc += xo * wc;
                }
            }
        }
    }

    // ---- block-wide reduce of pool_acc -> partial[blk] ----
    float* red = (float*)&p_lds[0][0];   // 512 floats = 2 KB, p_lds is free now
    red[t] = pool_acc;
    __syncthreads();
    #pragma unroll
    for (int s = 256; s > 0; s >>= 1) {
        if (t < s) red[t] += red[t + s];
        __syncthreads();
    }
    if (t == 0) partial[blk] = red[0];
}

// ---- final: out[b] = b_comb + sum of 4 block partials ----
__global__ void final_kernel(const float* __restrict__ partial,
                             const float* __restrict__ bcomb,
                             float* __restrict__ out) {
    int b = threadIdx.x;  // 0..63
    out[b] = bcomb[0] + partial[4*b] + partial[4*b+1] + partial[4*b+2] + partial[4*b+3];
}

extern "C" void kernel_launch(void* const* d_in, const int* in_sizes, int n_in,
                              void* d_out, int out_size, void* d_ws, size_t ws_size,
                              hipStream_t stream) {
    const float* x     = (const float*)d_in[0];
    const float* dist  = (const float*)d_in[1];
    const float* wcf_w = (const float*)d_in[2];
    const float* wcf_b = (const float*)d_in[3];
    const float* wdf_w = (const float*)d_in[4];
    const float* wdf_b = (const float*)d_in[5];
    const float* wfc_w = (const float*)d_in[6];
    const float* fc0_w = (const float*)d_in[7];
    const float* fc0_b = (const float*)d_in[8];
    const float* out_w = (const float*)d_in[9];
    const float* out_b = (const float*)d_in[10];
    float* out = (float*)d_out;

    char* ws = (char*)d_ws;
    unsigned short* wcfb = (unsigned short*)(ws);                   // 196608 B
    unsigned short* wdfb = (unsigned short*)(ws + 196608u);         //  98304 B
    unsigned short* wfcb = (unsigned short*)(ws + 294912u);         // 196608 B
    float* wcomb   = (float*)(ws + 491520u);                        // 512 B
    float* bcomb   = (float*)(ws + 492032u);                        // 512 B
    float* partial = (float*)(ws + 492544u);                        // 1024 B

    prep_w_kernel<<<240, 256, 0, stream>>>(wcf_w, wdf_w, wfc_w, wcfb, wdfb, wfcb);
    prep_comb_kernel<<<1, 128, 0, stream>>>(fc0_w, fc0_b, out_w, out_b, wcomb, bcomb);

    mega_kernel<<<M_/32, 512, 0, stream>>>(x, dist, wcfb, wdfb, wfcb,
                                           wcf_b, wdf_b, wcomb, partial);

    final_kernel<<<1, 64, 0, stream>>>(partial, bcomb, out);
}

// Round 3
// 78.306 us; speedup vs baseline: 1.5726x; 1.3370x over previous
//
#include <hip/hip_runtime.h>
#include <math.h>

#define B_ 64
#define N_ 128
#define F_ 128
#define R_ 64
#define H_ 256
#define L_ 3
#define M_ (B_*N_)   // 8192 rows

#define DS_PAD 72    // row stride for ds_lds (144 B, 16B-aligned rows)
#define X_PAD 136    // row stride for x_lds  (272 B = 17*16)
#define P_PAD 264    // row stride for p_lds  (528 B = 33*16)

#define PREPW_NBLK 48
#define COMB_BID   48
#define DSUM_BID0  49

typedef short bf16x8 __attribute__((ext_vector_type(8)));
typedef float f32x4 __attribute__((ext_vector_type(4)));

__device__ __forceinline__ unsigned short f2bf(float f) {
    unsigned int u = __float_as_uint(f);
    u += 0x7FFF + ((u >> 16) & 1);   // round-to-nearest-even
    return (unsigned short)(u >> 16);
}

__device__ __forceinline__ float tanh_fast(float h) {
    float a = fabsf(h);
    float e = __expf(-2.0f * a);                 // never overflows; ->0 for large a
    float t = (1.0f - e) * __builtin_amdgcn_rcpf(1.0f + e);
    return copysignf(t, h);
}

// ---- kernel 1: dsum (8192 row-blocks) + weight prep (48 blocks) + comb/out-init (1 block) ----
__global__ __launch_bounds__(256)
void dsum_prep_kernel(const float* __restrict__ dist,
                      const float* __restrict__ wcf,
                      const float* __restrict__ wdf,
                      const float* __restrict__ wfc,
                      const float* __restrict__ fc0_w, const float* __restrict__ fc0_b,
                      const float* __restrict__ out_w, const float* __restrict__ out_b,
                      unsigned short* __restrict__ wcfb,
                      unsigned short* __restrict__ wdfb,
                      unsigned short* __restrict__ wfcb,
                      float* __restrict__ wcomb,
                      unsigned short* __restrict__ dsumb,
                      float* __restrict__ out) {
    const int bid = blockIdx.x;
    const int t   = threadIdx.x;

    if (bid < PREPW_NBLK) {
        // fp32 -> bf16 for the 3 stacked weight tensors (61440 float4 over 12288 threads)
        const int NCF = L_*H_*F_/4;  // 24576
        const int NDF = L_*H_*R_/4;  // 12288
        const int NFC = L_*F_*H_/4;  // 24576
        const int total = NCF + NDF + NFC;
        for (int i = bid*256 + t; i < total; i += PREPW_NBLK*256) {
            const float4* src; unsigned short* dst; int k;
            if (i < NCF)           { src = (const float4*)wcf; dst = wcfb; k = i; }
            else if (i < NCF+NDF)  { src = (const float4*)wdf; dst = wdfb; k = i-NCF; }
            else                   { src = (const float4*)wfc; dst = wfcb; k = i-NCF-NDF; }
            float4 v = src[k];
            ushort4 o; o.x=f2bf(v.x); o.y=f2bf(v.y); o.z=f2bf(v.z); o.w=f2bf(v.w);
            ((ushort4*)dst)[k] = o;
        }
        return;
    }
    if (bid == COMB_BID) {
        if (t < 128) {
            // w_comb[f] = sum_c out_w[c]*fc0_w[c,f]
            float s = 0.f;
            #pragma unroll 8
            for (int c = 0; c < 256; ++c) s += out_w[c] * fc0_w[c*128 + t];
            wcomb[t] = s;
        } else if (t < 192) {
            // out[b] = b_comb (init; layers kernel atomically accumulates on top)
            float bb = out_b[0];
            #pragma unroll 8
            for (int c = 0; c < 256; ++c) bb += out_w[c] * fc0_b[c];
            out[t - 128] = bb;
        }
        return;
    }

    // ---- dsum for one row: dsumb[row,r] = sum_j dist[row,j,r] ----
    const int row = bid - DSUM_BID0;
    const float4* src = (const float4*)(dist + (size_t)row * (N_*R_));
    const int q = t & 15, jg = t >> 4;           // q: float4 col (16/row), jg: j-group
    float4 a = make_float4(0.f,0.f,0.f,0.f);
    #pragma unroll
    for (int j0 = 0; j0 < N_; j0 += 16) {
        float4 v = src[(j0 + jg)*16 + q];
        a.x += v.x; a.y += v.y; a.z += v.z; a.w += v.w;
    }
    __shared__ float4 sh[256];
    sh[t] = a;
    __syncthreads();
    if (t < 16) {
        float4 s = sh[t];
        for (int g = 1; g < 16; ++g) {
            float4 v = sh[t + 16*g];
            s.x += v.x; s.y += v.y; s.z += v.z; s.w += v.w;
        }
        ushort4 o; o.x=f2bf(s.x); o.y=f2bf(s.y); o.z=f2bf(s.z); o.w=f2bf(s.w);
        ((ushort4*)(dsumb + (size_t)row * R_))[t] = o;
    }
}

// ---- kernel 2: fused 3 DTNN layers + pooled partial, one block per 32 rows ----
// 512 threads = 8 waves: mh = w&1 (16-row half), nq = w>>1 (col quarter).
__global__ __launch_bounds__(512)
void layers_kernel(const float* __restrict__ x,
                   const unsigned short* __restrict__ dsumb,
                   const unsigned short* __restrict__ wcfb,
                   const unsigned short* __restrict__ wdfb,
                   const unsigned short* __restrict__ wfcb,
                   const float* __restrict__ bcf,
                   const float* __restrict__ bdf,
                   const float* __restrict__ wcomb,
                   float* __restrict__ out) {
    __shared__ __align__(16) unsigned short ds_lds[32][DS_PAD];
    __shared__ __align__(16) unsigned short x_lds[32][X_PAD];
    __shared__ __align__(16) unsigned short p_lds[32][P_PAD];

    const int blk  = blockIdx.x;
    const int t    = threadIdx.x;
    const int w    = t >> 6, lane = t & 63;
    const int lr   = lane & 15, lg = lane >> 4;
    const int mh   = w & 1,  nq = w >> 1;        // nq in 0..3

    // ---- load x (fp32 -> bf16) and dsum (bf16) into LDS ----
    {
        const int row16 = t >> 4, q = t & 15;    // 32 rows x 16 float4-cols
        const float4* xs = (const float4*)(x + (size_t)(blk*32 + row16)*F_ + q*8);
        float4 xv0 = xs[0], xv1 = xs[1];
        bf16x8 xb;
        xb[0]=f2bf(xv0.x); xb[1]=f2bf(xv0.y); xb[2]=f2bf(xv0.z); xb[3]=f2bf(xv0.w);
        xb[4]=f2bf(xv1.x); xb[5]=f2bf(xv1.y); xb[6]=f2bf(xv1.z); xb[7]=f2bf(xv1.w);
        *(bf16x8*)&x_lds[row16][q*8] = xb;

        if (t < 256) {                           // 32 rows x 8 chunks of 16B
            const uint4* dsrc = (const uint4*)(dsumb + (size_t)(blk*32 + (t>>3))*R_);
            uint4 v = dsrc[t & 7];
            *(uint4*)&ds_lds[t>>3][(t&7)*8] = v;
        }
    }
    __syncthreads();

    float pool_acc = 0.f;

    #pragma unroll 1
    for (int l = 0; l < L_; ++l) {
        const unsigned short* wcf = wcfb + l*H_*F_;
        const unsigned short* wdf = wdfb + l*H_*R_;
        const unsigned short* wfc = wfcb + l*F_*H_;

        // A-fragments from LDS: lane holds A[lr][kc*32 + lg*8 + j]
        bf16x8 xa[4], da[2];
        #pragma unroll
        for (int kc = 0; kc < 4; ++kc)
            xa[kc] = *(const bf16x8*)&x_lds[mh*16 + lr][kc*32 + lg*8];
        #pragma unroll
        for (int kc = 0; kc < 2; ++kc)
            da[kc] = *(const bf16x8*)&ds_lds[mh*16 + lr][kc*32 + lg*8];

        // stage 1: wave covers 16 rows x 64 cols of p (H=256 split 4 ways by nq)
        #pragma unroll
        for (int nt = 0; nt < 4; ++nt) {
            const int ncol = nq*64 + nt*16 + lr;
            f32x4 acf = {0.f,0.f,0.f,0.f}, adf = {0.f,0.f,0.f,0.f};
            #pragma unroll
            for (int kc = 0; kc < 4; ++kc) {
                bf16x8 b = *(const bf16x8*)(wcf + (size_t)ncol*F_ + kc*32 + lg*8);
                acf = __builtin_amdgcn_mfma_f32_16x16x32_bf16(xa[kc], b, acf, 0, 0, 0);
            }
            #pragma unroll
            for (int kc = 0; kc < 2; ++kc) {
                bf16x8 b = *(const bf16x8*)(wdf + (size_t)ncol*R_ + kc*32 + lg*8);
                adf = __builtin_amdgcn_mfma_f32_16x16x32_bf16(da[kc], b, adf, 0, 0, 0);
            }
            const float bc = bcf[l*H_ + ncol];
            const float bd = bdf[l*H_ + ncol] * 128.0f;   // n * Wdf_b, n = N = 128
            #pragma unroll
            for (int j = 0; j < 4; ++j) {
                float p = (acf[j] + bc) * (adf[j] + bd);
                p_lds[mh*16 + lg*4 + j][ncol] = f2bf(p);
            }
        }
        __syncthreads();

        // stage 2: h(32x128) = p(32x256) @ Wfc^T; wave covers 32 cols (nq quarter)
        f32x4 ah[2] = {{0,0,0,0},{0,0,0,0}};
        #pragma unroll
        for (int kc = 0; kc < 8; ++kc) {
            bf16x8 ap = *(const bf16x8*)&p_lds[mh*16 + lr][kc*32 + lg*8];
            #pragma unroll
            for (int ct = 0; ct < 2; ++ct) {
                const int ncol = nq*32 + ct*16 + lr;
                bf16x8 b = *(const bf16x8*)(wfc + (size_t)ncol*H_ + kc*32 + lg*8);
                ah[ct] = __builtin_amdgcn_mfma_f32_16x16x32_bf16(ap, b, ah[ct], 0, 0, 0);
            }
        }
        __syncthreads();   // p_lds consumed

        if (l < L_-1) {
            #pragma unroll
            for (int ct = 0; ct < 2; ++ct) {
                #pragma unroll
                for (int j = 0; j < 4; ++j) {
                    float h = ah[ct][j];
                    float xo = h + tanh_fast(h);
                    // D layout: row = mh*16 + lg*4 + j, col = nq*32 + ct*16 + lr
                    x_lds[mh*16 + lg*4 + j][nq*32 + ct*16 + lr] = f2bf(xo);
                }
            }
            __syncthreads();
        } else {
            #pragma unroll
            for (int ct = 0; ct < 2; ++ct) {
                const float wc = wcomb[nq*32 + ct*16 + lr];
                #pragma unroll
                for (int j = 0; j < 4; ++j) {
                    float h = ah[ct][j];
                    float xo = h + tanh_fast(h);
                    pool_acc += xo * wc;
                }
            }
        }
    }

    // ---- block-wide reduce of pool_acc; one atomicAdd per block into out[b] ----
    float* red = (float*)&p_lds[0][0];   // 512 floats, p_lds is free now
    red[t] = pool_acc;
    __syncthreads();
    #pragma unroll
    for (int s = 256; s > 0; s >>= 1) {
        if (t < s) red[t] += red[t + s];
        __syncthreads();
    }
    if (t == 0) atomicAdd(&out[blk >> 2], red[0]);   // 4 blocks per batch b
}

extern "C" void kernel_launch(void* const* d_in, const int* in_sizes, int n_in,
                              void* d_out, int out_size, void* d_ws, size_t ws_size,
                              hipStream_t stream) {
    const float* x     = (const float*)d_in[0];
    const float* dist  = (const float*)d_in[1];
    const float* wcf_w = (const float*)d_in[2];
    const float* wcf_b = (const float*)d_in[3];
    const float* wdf_w = (const float*)d_in[4];
    const float* wdf_b = (const float*)d_in[5];
    const float* wfc_w = (const float*)d_in[6];
    const float* fc0_w = (const float*)d_in[7];
    const float* fc0_b = (const float*)d_in[8];
    const float* out_w = (const float*)d_in[9];
    const float* out_b = (const float*)d_in[10];
    float* out = (float*)d_out;

    char* ws = (char*)d_ws;
    unsigned short* wcfb  = (unsigned short*)(ws);                  // 196608 B
    unsigned short* wdfb  = (unsigned short*)(ws + 196608u);        //  98304 B
    unsigned short* wfcb  = (unsigned short*)(ws + 294912u);        // 196608 B
    float*          wcomb = (float*)(ws + 491520u);                 //    512 B
    unsigned short* dsumb = (unsigned short*)(ws + 492032u);        // 1 MB

    dsum_prep_kernel<<<DSUM_BID0 + M_, 256, 0, stream>>>(
        dist, wcf_w, wdf_w, wfc_w, fc0_w, fc0_b, out_w, out_b,
        wcfb, wdfb, wfcb, wcomb, dsumb, out);

    layers_kernel<<<M_/32, 512, 0, stream>>>(x, dsumb, wcfb, wdfb, wfcb,
                                             wcf_b, wdf_b, wcomb, out);
}